// Round 1
// baseline (204.540 us; speedup 1.0000x reference)
//
#include <hip/hip_runtime.h>
#include <hip/hip_bf16.h>
#include <cstdint>
#include <cstddef>

// Problem dims (all fixed): B=4, NI=NO=256, DIN=DQ=DH=DOUT=256.
// out[b,i,j,:] = gelu(u[b,i,:] + v[b,j,:]) @ W2 + b2
//   u = (x@W_pre + b_pre)@W1[:256] + b1     (b1 folded into u)
//   v = (query@W_emb + b_emb)@W1[256:]

typedef __bf16  bf16x8 __attribute__((ext_vector_type(8)));
typedef float   f32x4  __attribute__((ext_vector_type(4)));

// ---------------------------------------------------------------------------
// Pre-kernel: two chained 256x256 GEMMs per row block.
// outp[r, n] = (A[r,:] @ Wa + ba)[k] @ W1p[k, n]  (+ b1p)
// 8 rows per block, 256 threads (thread = output column n).
// ---------------------------------------------------------------------------
__global__ __launch_bounds__(256) void pre_kernel(
    const float* __restrict__ A, const float* __restrict__ Wa,
    const float* __restrict__ ba, const float* __restrict__ W1p,
    const float* __restrict__ b1p, float* __restrict__ outp)
{
    __shared__ float as[8][256];
    __shared__ float xs[8][256];
    const int t  = threadIdx.x;
    const int r0 = blockIdx.x * 8;

#pragma unroll
    for (int r = 0; r < 8; ++r)
        as[r][t] = A[(size_t)(r0 + r) * 256 + t];
    __syncthreads();

    float acc[8] = {0.f,0.f,0.f,0.f,0.f,0.f,0.f,0.f};
    for (int k = 0; k < 256; ++k) {
        const float wv = Wa[(size_t)k * 256 + t];
#pragma unroll
        for (int r = 0; r < 8; ++r) acc[r] += as[r][k] * wv;
    }
    const float bav = ba[t];
#pragma unroll
    for (int r = 0; r < 8; ++r) xs[r][t] = acc[r] + bav;
    __syncthreads();

    float acc2[8] = {0.f,0.f,0.f,0.f,0.f,0.f,0.f,0.f};
    for (int k = 0; k < 256; ++k) {
        const float wv = W1p[(size_t)k * 256 + t];
#pragma unroll
        for (int r = 0; r < 8; ++r) acc2[r] += xs[r][k] * wv;
    }
    const float b1v = b1p ? b1p[t] : 0.f;
#pragma unroll
    for (int r = 0; r < 8; ++r)
        outp[(size_t)(r0 + r) * 256 + t] = acc2[r] + b1v;
}

// ---------------------------------------------------------------------------
// W2 transpose + bf16 convert: W2T[n][k] = bf16(W2[k][n]).  (256x256, tiny)
// ---------------------------------------------------------------------------
__global__ __launch_bounds__(256) void w2t_kernel(
    const float* __restrict__ W2, unsigned short* __restrict__ W2T)
{
    const int n = blockIdx.x;
    const int k = threadIdx.x;
    const float wv = W2[(size_t)k * 256 + n];
    const __bf16 bv = (__bf16)wv;
    W2T[(size_t)n * 256 + k] = __builtin_bit_cast(unsigned short, bv);
}

// ---------------------------------------------------------------------------
// Fused main kernel.
// Block = 256 threads = 4 waves. Block computes 64 output rows (fixed b,i;
// j0..j0+63) x all 256 cols. Wave w owns rows [w*16, w*16+16).
// mfma_f32_16x16x32_bf16 layouts (gfx950):
//   A: lane l holds A[l%16][(l/16)*8 + e], e=0..7
//   B: lane l holds B[(l/16)*8 + e][l%16]
//   D: lane l reg r holds D[(l/16)*4 + r][l%16]
// A-fragments (H rows) are generated in-register per-lane: each lane computes
// gelu(u+v) for exactly its fragment elements -> no LDS, no duplication.
// W2T staged in LDS per 64-k chunk, XOR-swizzled for conflict-free b128 reads.
// ---------------------------------------------------------------------------
__global__ __launch_bounds__(256) void fused_kernel(
    const float* __restrict__ U, const float* __restrict__ V,
    const unsigned short* __restrict__ W2T, const float* __restrict__ b2,
    float* __restrict__ out)
{
    __shared__ uint4 wlds[2048];              // 32 KB: [256 n][64 k] bf16, swizzled

    const int t    = threadIdx.x;
    const int lane = t & 63;
    const int w    = t >> 6;
    const int l15  = lane & 15;
    const int kg   = lane >> 4;               // 0..3

    const size_t r0 = (size_t)blockIdx.x * 64;
    const int bb = (int)(r0 >> 16);
    const int ii = (int)((r0 >> 8) & 255);
    const int j0 = (int)(r0 & 255);

    const float* __restrict__ urow = U + ((size_t)(bb * 256 + ii)) * 256;
    const int jA = j0 + w * 16 + l15;         // this lane's A-row (j index)
    const float* __restrict__ vrow = V + ((size_t)(bb * 256 + jA)) * 256;

    f32x4 acc[16];
    const f32x4 zero = {0.f, 0.f, 0.f, 0.f};
#pragma unroll
    for (int i = 0; i < 16; ++i) acc[i] = zero;

    for (int kk = 0; kk < 256; kk += 64) {
        __syncthreads();
        // stage W2T chunk [256 n][64 k] into LDS, XOR-swizzled (16B granules)
#pragma unroll
        for (int it = 0; it < 8; ++it) {
            const int idx = it * 256 + t;
            const int n   = idx >> 3;         // 0..255
            const int kgc = idx & 7;          // 0..7 (8 bf16 each)
            const uint4 val = *reinterpret_cast<const uint4*>(
                W2T + (size_t)n * 256 + kk + kgc * 8);
            wlds[n * 8 + (kgc ^ (n & 7))] = val;
        }
        __syncthreads();

#pragma unroll
        for (int s = 0; s < 2; ++s) {
            const int k0 = kk + s * 32;
            // --- A fragment: gelu(u+v) for 8 k-values, in-register ---
            const float4* up = reinterpret_cast<const float4*>(urow + k0 + kg * 8);
            const float4* vp = reinterpret_cast<const float4*>(vrow + k0 + kg * 8);
            const float4 u0 = up[0], u1 = up[1];
            const float4 v0 = vp[0], v1 = vp[1];
            float hv[8] = {u0.x + v0.x, u0.y + v0.y, u0.z + v0.z, u0.w + v0.w,
                           u1.x + v1.x, u1.y + v1.y, u1.z + v1.z, u1.w + v1.w};
            bf16x8 afrag;
#pragma unroll
            for (int e = 0; e < 8; ++e) {
                const float xv = hv[e];
                const float g  = 0.5f * xv * (1.0f + erff(xv * 0.70710678118654752f));
                afrag[e] = (__bf16)g;
            }
            const int kgc_r = s * 4 + kg;
            // --- 16 B fragments from LDS + 16 MFMAs ---
#pragma unroll
            for (int nf = 0; nf < 16; ++nf) {
                const int col = nf * 16 + l15;
                const bf16x8 bfrag = __builtin_bit_cast(
                    bf16x8, wlds[col * 8 + (kgc_r ^ (col & 7))]);
                acc[nf] = __builtin_amdgcn_mfma_f32_16x16x32_bf16(
                    afrag, bfrag, acc[nf], 0, 0, 0);
            }
        }
    }

    // epilogue: out[row][col] = acc + b2[col]
    const int drow = w * 16 + kg * 4;
#pragma unroll
    for (int nf = 0; nf < 16; ++nf) {
        const int col = nf * 16 + l15;
        const float bv = b2[col];
#pragma unroll
        for (int r = 0; r < 4; ++r) {
            const size_t row = r0 + drow + r;
            out[row * 256 + col] = acc[nf][r] + bv;
        }
    }
}

// ---------------------------------------------------------------------------
extern "C" void kernel_launch(void* const* d_in, const int* in_sizes, int n_in,
                              void* d_out, int out_size, void* d_ws, size_t ws_size,
                              hipStream_t stream)
{
    const float* x     = (const float*)d_in[0];
    const float* query = (const float*)d_in[1];
    const float* W_pre = (const float*)d_in[2];
    const float* b_pre = (const float*)d_in[3];
    const float* W_emb = (const float*)d_in[4];
    const float* b_emb = (const float*)d_in[5];
    const float* W1    = (const float*)d_in[6];
    const float* b1    = (const float*)d_in[7];
    const float* W2    = (const float*)d_in[8];
    const float* b2    = (const float*)d_in[9];
    float* out = (float*)d_out;

    char* ws = (char*)d_ws;
    float* u            = (float*)(ws);                     // 1 MB (4*256*256 f32)
    float* v            = (float*)(ws + (1 << 20));         // 1 MB
    unsigned short* w2t = (unsigned short*)(ws + 2 * (1 << 20)); // 128 KB

    // u = (x@W_pre+b_pre)@W1x + b1 ; v = (query@W_emb+b_emb)@W1c
    pre_kernel<<<128, 256, 0, stream>>>(x,     W_pre, b_pre, W1,              b1,      u);
    pre_kernel<<<128, 256, 0, stream>>>(query, W_emb, b_emb, W1 + 256 * 256,  nullptr, v);
    w2t_kernel<<<256, 256, 0, stream>>>(W2, w2t);
    fused_kernel<<<4096, 256, 0, stream>>>(u, v, w2t, b2, out);
}

// Round 2
// 112.702 us; speedup vs baseline: 1.8149x; 1.8149x over previous
//
#include <hip/hip_runtime.h>
#include <hip/hip_bf16.h>
#include <cstdint>
#include <cstddef>

// Problem dims (fixed): B=4, NI=NO=256, DIN=DQ=DH=DOUT=256.
// out[b,i,j,:] = gelu(u[b,i,:] + v[b,j,:]) @ W2 + b2
//   u = (x@W_pre + b_pre)@W1[:256] + b1   (b1 folded into u)
//   v = (query@W_emb + b_emb)@W1[256:]

typedef __bf16  bf16x8 __attribute__((ext_vector_type(8)));
typedef float   f32x16 __attribute__((ext_vector_type(16)));

// tanh-approx gelu: x * sigmoid(1.5957691*x + 0.0713548*x^3)
// max |err| vs exact gelu ~3e-3; 1 v_exp + 1 v_rcp + 6 full-rate ops.
__device__ __forceinline__ float fast_gelu(float x) {
    const float x2 = x * x;
    const float t  = __builtin_fmaf(x2, 0.07135481283f, 1.5957691216f);
    const float e  = __builtin_amdgcn_exp2f(x * t * -1.442695041f);
    return x * __builtin_amdgcn_rcpf(1.0f + e);
}

// ---------------------------------------------------------------------------
// Prep kernel (one launch):
//   blocks [0,256):   u rows — x path (4 rows/block)
//   blocks [256,512): v rows — query path
//   blocks [512,576): W2T[n][k] = bf16(W2[k][n])  (4 n-cols/block)
// ---------------------------------------------------------------------------
__global__ __launch_bounds__(256) void prep_kernel(
    const float* __restrict__ x, const float* __restrict__ query,
    const float* __restrict__ W_pre, const float* __restrict__ b_pre,
    const float* __restrict__ W_emb, const float* __restrict__ b_emb,
    const float* __restrict__ W1, const float* __restrict__ b1,
    const float* __restrict__ W2,
    float* __restrict__ u, float* __restrict__ v,
    unsigned short* __restrict__ w2t)
{
    const int b = blockIdx.x;
    const int t = threadIdx.x;

    if (b >= 512) {                       // W2 transpose + bf16 convert
        const int n0 = (b - 512) * 4;
        const float4 wv = *reinterpret_cast<const float4*>(W2 + (size_t)t * 256 + n0);
        const float vals[4] = {wv.x, wv.y, wv.z, wv.w};
#pragma unroll
        for (int j = 0; j < 4; ++j) {
            const __bf16 bv = (__bf16)vals[j];
            w2t[(size_t)(n0 + j) * 256 + t] = __builtin_bit_cast(unsigned short, bv);
        }
        return;
    }

    const bool isq = (b >= 256);
    const float* __restrict__ A   = isq ? query : x;
    const float* __restrict__ Wa  = isq ? W_emb : W_pre;
    const float* __restrict__ ba  = isq ? b_emb : b_pre;
    const float* __restrict__ W1p = isq ? (W1 + 256 * 256) : W1;
    float* __restrict__ outp      = isq ? v : u;
    const int r0 = (isq ? (b - 256) : b) * 4;

    __shared__ float as[4][256];
    __shared__ float xs[4][256];

#pragma unroll
    for (int r = 0; r < 4; ++r)
        as[r][t] = A[(size_t)(r0 + r) * 256 + t];
    __syncthreads();

    float acc[4] = {0.f, 0.f, 0.f, 0.f};
    for (int k = 0; k < 256; ++k) {
        const float wv = Wa[(size_t)k * 256 + t];
#pragma unroll
        for (int r = 0; r < 4; ++r) acc[r] += as[r][k] * wv;
    }
    const float bav = ba[t];
#pragma unroll
    for (int r = 0; r < 4; ++r) xs[r][t] = acc[r] + bav;
    __syncthreads();

    float acc2[4] = {0.f, 0.f, 0.f, 0.f};
    for (int k = 0; k < 256; ++k) {
        const float wv = W1p[(size_t)k * 256 + t];
#pragma unroll
        for (int r = 0; r < 4; ++r) acc2[r] += xs[r][k] * wv;
    }
    const float b1v = isq ? 0.f : b1[t];
#pragma unroll
    for (int r = 0; r < 4; ++r)
        outp[(size_t)(r0 + r) * 256 + t] = acc2[r] + b1v;
}

// ---------------------------------------------------------------------------
// Fused main kernel.
// Block = 256 threads = 4 waves; computes 128 output rows (fixed b,i; 128 j)
// x 256 cols. Wave w owns rows [w*32, w*32+32) as ONE 32-row A operand.
// mfma_f32_32x32x16_bf16 layouts (gfx950):
//   A: lane l holds A[l&31][(l>>5)*8 + e]          (e = 0..7)
//   B: lane l holds B[(l>>5)*8 + e][l&31]
//   D: lane l reg r holds D[(r&3) + 8*(r>>2) + 4*(l>>5)][l&31]
// A-fragments (H rows) generated in-register per lane: gelu(u+v), each H
// element computed by exactly one lane. W2T staged in LDS per 64-k chunk,
// XOR-swizzled (measured 0 bank conflicts with this pattern).
// ---------------------------------------------------------------------------
__global__ __launch_bounds__(256, 2) void fused_kernel(
    const float* __restrict__ U, const float* __restrict__ V,
    const unsigned short* __restrict__ W2T, const float* __restrict__ b2,
    float* __restrict__ out)
{
    __shared__ uint4 wlds[2048];              // 32 KB: [256 n][64 k] bf16, swizzled

    const int t    = threadIdx.x;
    const int lane = t & 63;
    const int w    = t >> 6;
    const int l31  = lane & 31;
    const int hi   = lane >> 5;               // 0..1

    const size_t r0 = (size_t)blockIdx.x * 128;
    const int bb = (int)(r0 >> 16);
    const int ii = (int)((r0 >> 8) & 255);
    const int j0 = (int)(r0 & 255);           // 0 or 128

    const float* __restrict__ urow = U + ((size_t)(bb * 256 + ii)) * 256;
    const int jA = j0 + w * 32 + l31;         // this lane's A-row (j index)
    const float* __restrict__ vrow = V + ((size_t)(bb * 256 + jA)) * 256;

    f32x16 acc[8];
#pragma unroll
    for (int i = 0; i < 8; ++i) acc[i] = (f32x16)0.f;

    for (int kk = 0; kk < 256; kk += 64) {
        __syncthreads();
        // stage W2T chunk [256 n][64 k] into LDS, XOR-swizzled 16B granules
#pragma unroll
        for (int it = 0; it < 8; ++it) {
            const int idx = it * 256 + t;
            const int n   = idx >> 3;         // 0..255
            const int g   = idx & 7;          // granule within row
            wlds[n * 8 + (g ^ (n & 7))] = *reinterpret_cast<const uint4*>(
                W2T + (size_t)n * 256 + kk + g * 8);
        }
        __syncthreads();

#pragma unroll
        for (int s = 0; s < 4; ++s) {
            const int k0 = kk + s * 16;
            // --- A fragment: gelu(u+v) for 8 k-values, in-register ---
            const float4 u0 = *reinterpret_cast<const float4*>(urow + k0 + hi * 8);
            const float4 u1 = *reinterpret_cast<const float4*>(urow + k0 + hi * 8 + 4);
            const float4 v0 = *reinterpret_cast<const float4*>(vrow + k0 + hi * 8);
            const float4 v1 = *reinterpret_cast<const float4*>(vrow + k0 + hi * 8 + 4);
            const float hv[8] = {u0.x + v0.x, u0.y + v0.y, u0.z + v0.z, u0.w + v0.w,
                                 u1.x + v1.x, u1.y + v1.y, u1.z + v1.z, u1.w + v1.w};
            bf16x8 afrag;
#pragma unroll
            for (int e = 0; e < 8; ++e)
                afrag[e] = (__bf16)fast_gelu(hv[e]);

            const int gk = s * 2 + hi;        // k-granule index within chunk
#pragma unroll
            for (int cg = 0; cg < 8; ++cg) {
                const int col = cg * 32 + l31;
                const bf16x8 bfrag = __builtin_bit_cast(
                    bf16x8, wlds[col * 8 + (gk ^ (col & 7))]);
                acc[cg] = __builtin_amdgcn_mfma_f32_32x32x16_bf16(
                    afrag, bfrag, acc[cg], 0, 0, 0);
            }
        }
    }

    // epilogue: out[row][col] = acc + b2[col]
#pragma unroll
    for (int cg = 0; cg < 8; ++cg) {
        const int col = cg * 32 + l31;
        const float bv = b2[col];
#pragma unroll
        for (int r = 0; r < 16; ++r) {
            const int row = w * 32 + 4 * hi + (r & 3) + 8 * (r >> 2);
            out[(r0 + row) * 256 + col] = acc[cg][r] + bv;
        }
    }
}

// ---------------------------------------------------------------------------
extern "C" void kernel_launch(void* const* d_in, const int* in_sizes, int n_in,
                              void* d_out, int out_size, void* d_ws, size_t ws_size,
                              hipStream_t stream)
{
    const float* x     = (const float*)d_in[0];
    const float* query = (const float*)d_in[1];
    const float* W_pre = (const float*)d_in[2];
    const float* b_pre = (const float*)d_in[3];
    const float* W_emb = (const float*)d_in[4];
    const float* b_emb = (const float*)d_in[5];
    const float* W1    = (const float*)d_in[6];
    const float* b1    = (const float*)d_in[7];
    const float* W2    = (const float*)d_in[8];
    const float* b2    = (const float*)d_in[9];
    float* out = (float*)d_out;

    char* ws = (char*)d_ws;
    float* u            = (float*)(ws);                          // 1 MB
    float* v            = (float*)(ws + (1 << 20));              // 1 MB
    unsigned short* w2t = (unsigned short*)(ws + 2 * (1 << 20)); // 128 KB

    prep_kernel<<<576, 256, 0, stream>>>(x, query, W_pre, b_pre, W_emb, b_emb,
                                         W1, b1, W2, u, v, w2t);
    fused_kernel<<<2048, 256, 0, stream>>>(u, v, w2t, b2, out);
}